// Round 2
// baseline (3790.955 us; speedup 1.0000x reference)
//
#include <hip/hip_runtime.h>

// LSTM: B=2048, T=512, I=1, H=64, L=2, O=1. All fp32.
// Fused 2-layer persistent kernel, round 2:
//   - 256 blocks x 256 threads, BT=8 batch/block -> exactly 1 block/CU, single pass.
//   - __launch_bounds__(256,1): up to 512 unified VGPRs/wave -> the 192
//     persistent weight floats per thread stay in registers (round 1 spilled
//     to AGPRs at the 128-reg cap and inflated VALU 2.5x).
//   - thread t owns gate-row t of Whh0 (64 regs) and of [Wih1|Whh1] (128 regs).
//   - h1/h2 in LDS (wave-uniform broadcast reads), c-state in registers
//     (2 (b,j) pairs per thread per layer).
//   - 4 barriers per timestep.

#define TT 512
#define HH 64
#define BT 8   // batch per block

__device__ __forceinline__ float sigm(float x) {
    return __builtin_amdgcn_rcpf(1.f + __expf(-x));
}
__device__ __forceinline__ float tanh_f(float x) {
    float xc = fminf(fmaxf(x, -15.f), 15.f);
    float e = __expf(2.f * xc);
    return (e - 1.f) * __builtin_amdgcn_rcpf(e + 1.f);
}
__device__ __forceinline__ float dot4(float4 a, float4 b, float acc) {
    acc = fmaf(a.x, b.x, acc);
    acc = fmaf(a.y, b.y, acc);
    acc = fmaf(a.z, b.z, acc);
    acc = fmaf(a.w, b.w, acc);
    return acc;
}

__global__ __launch_bounds__(256, 1) void lstm_fused(
    const float* __restrict__ x,
    const float* __restrict__ Wih0, const float* __restrict__ Whh0,
    const float* __restrict__ bih0, const float* __restrict__ bhh0,
    const float* __restrict__ Wih1, const float* __restrict__ Whh1,
    const float* __restrict__ bih1, const float* __restrict__ bhh1,
    const float* __restrict__ fcW, const float* __restrict__ fcb,
    float* __restrict__ out)
{
    __shared__ float  xs[BT * TT];        // 16KB: x tile, 8 rows x 512
    __shared__ float4 hc4[BT][32];        // per b: [h1(64) | h2(64)], 4KB
    __shared__ float  p[BT][256];         // gate preacts, 8KB
    __shared__ float  fcw_s[HH];

    const int t  = threadIdx.x;
    const int b0 = blockIdx.x * BT;

    // ---- stage x tile (coalesced float4): 8*512 floats = 1024 float4 ----
    {
        const float4* xg  = (const float4*)(x + (size_t)b0 * TT);
        float4*       xsl = (float4*)xs;
        #pragma unroll
        for (int i = 0; i < BT * TT / 4 / 256; ++i)
            xsl[t + i * 256] = xg[t + i * 256];
    }

    // ---- persistent per-thread weights (row t of each matrix): 192 VGPRs ----
    float4 w1[16], w2i[16], w2h[16];
    {
        const float4* r1 = (const float4*)(Whh0 + t * HH);
        const float4* ri = (const float4*)(Wih1 + t * HH);
        const float4* rh = (const float4*)(Whh1 + t * HH);
        #pragma unroll
        for (int k = 0; k < 16; ++k) { w1[k] = r1[k]; w2i[k] = ri[k]; w2h[k] = rh[k]; }
    }
    const float wx    = Wih0[t];
    const float bias1 = bih0[t] + bhh0[t];
    const float bias2 = bih1[t] + bhh1[t];
    if (t < HH) fcw_s[t] = fcW[t];

    // ---- zero h state ----
    {
        float4 z = make_float4(0.f, 0.f, 0.f, 0.f);
        float4* hcl = (float4*)hc4;
        if (t < BT * 32) hcl[t] = z;
    }
    // combine ownership: thread t handles (bA, jj) and (bB, jj), bB = bA+4
    const int jj = t & 63;
    const int bA = t >> 6;        // 0..3
    const int bB = bA + 4;        // 4..7
    float c1A = 0.f, c1B = 0.f, c2A = 0.f, c2B = 0.f;
    float* hcf = (float*)hc4;

    __syncthreads();

    for (int step = 0; step < TT; ++step) {
        // ---- layer-1 matvec: p[b][t] = bias1 + wx*x[b,step] + Whh0[t,:]·h1[b] ----
        #pragma unroll
        for (int b = 0; b < BT; ++b) {
            float a0 = 0.f, a1 = 0.f, a2 = 0.f, a3 = 0.f;
            #pragma unroll
            for (int kc = 0; kc < 16; kc += 4) {
                a0 = dot4(w1[kc + 0], hc4[b][kc + 0], a0);
                a1 = dot4(w1[kc + 1], hc4[b][kc + 1], a1);
                a2 = dot4(w1[kc + 2], hc4[b][kc + 2], a2);
                a3 = dot4(w1[kc + 3], hc4[b][kc + 3], a3);
            }
            p[b][t] = ((a0 + a1) + (a2 + a3)) + fmaf(wx, xs[b * TT + step], bias1);
        }
        __syncthreads();

        // ---- layer-1 gate combine (2 pairs per thread) ----
        {
            float giA = sigm(p[bA][jj]);
            float gfA = sigm(p[bA][64 + jj]);
            float ggA = tanh_f(p[bA][128 + jj]);
            float goA = sigm(p[bA][192 + jj]);
            float giB = sigm(p[bB][jj]);
            float gfB = sigm(p[bB][64 + jj]);
            float ggB = tanh_f(p[bB][128 + jj]);
            float goB = sigm(p[bB][192 + jj]);
            c1A = fmaf(gfA, c1A, giA * ggA);
            c1B = fmaf(gfB, c1B, giB * ggB);
            hcf[bA * 128 + jj] = goA * tanh_f(c1A);
            hcf[bB * 128 + jj] = goB * tanh_f(c1B);
        }
        __syncthreads();

        // ---- layer-2 matvec: p[b][t] = bias2 + Wih1[t,:]·h1[b] + Whh1[t,:]·h2[b] ----
        #pragma unroll
        for (int b = 0; b < BT; ++b) {
            float a0 = 0.f, a1 = 0.f, a2 = 0.f, a3 = 0.f;
            #pragma unroll
            for (int kc = 0; kc < 16; kc += 4) {
                a0 = dot4(w2i[kc + 0], hc4[b][kc + 0], a0);
                a1 = dot4(w2i[kc + 1], hc4[b][kc + 1], a1);
                a2 = dot4(w2i[kc + 2], hc4[b][kc + 2], a2);
                a3 = dot4(w2i[kc + 3], hc4[b][kc + 3], a3);
            }
            #pragma unroll
            for (int kc = 0; kc < 16; kc += 4) {
                a0 = dot4(w2h[kc + 0], hc4[b][16 + kc + 0], a0);
                a1 = dot4(w2h[kc + 1], hc4[b][16 + kc + 1], a1);
                a2 = dot4(w2h[kc + 2], hc4[b][16 + kc + 2], a2);
                a3 = dot4(w2h[kc + 3], hc4[b][16 + kc + 3], a3);
            }
            p[b][t] = ((a0 + a1) + (a2 + a3)) + bias2;
        }
        __syncthreads();

        // ---- layer-2 gate combine ----
        {
            float giA = sigm(p[bA][jj]);
            float gfA = sigm(p[bA][64 + jj]);
            float ggA = tanh_f(p[bA][128 + jj]);
            float goA = sigm(p[bA][192 + jj]);
            float giB = sigm(p[bB][jj]);
            float gfB = sigm(p[bB][64 + jj]);
            float ggB = tanh_f(p[bB][128 + jj]);
            float goB = sigm(p[bB][192 + jj]);
            c2A = fmaf(gfA, c2A, giA * ggA);
            c2B = fmaf(gfB, c2B, giB * ggB);
            hcf[bA * 128 + 64 + jj] = goA * tanh_f(c2A);
            hcf[bB * 128 + 64 + jj] = goB * tanh_f(c2B);
        }
        __syncthreads();
    }

    // ---- final FC: out[b] = fcW · h2_final[b] + fcb ----
    if (t < BT) {
        float s = fcb[0];
        #pragma unroll
        for (int j = 0; j < HH; ++j)
            s = fmaf(hcf[t * 128 + 64 + j], fcw_s[j], s);
        out[b0 + t] = s;
    }
}

extern "C" void kernel_launch(void* const* d_in, const int* in_sizes, int n_in,
                              void* d_out, int out_size, void* d_ws, size_t ws_size,
                              hipStream_t stream) {
    const float* x    = (const float*)d_in[0];
    const float* Wih0 = (const float*)d_in[1];
    const float* Whh0 = (const float*)d_in[2];
    const float* bih0 = (const float*)d_in[3];
    const float* bhh0 = (const float*)d_in[4];
    const float* Wih1 = (const float*)d_in[5];
    const float* Whh1 = (const float*)d_in[6];
    const float* bih1 = (const float*)d_in[7];
    const float* bhh1 = (const float*)d_in[8];
    const float* fcW  = (const float*)d_in[9];
    const float* fcb  = (const float*)d_in[10];
    float* out = (float*)d_out;

    lstm_fused<<<dim3(2048 / BT), dim3(256), 0, stream>>>(
        x, Wih0, Whh0, bih0, bhh0, Wih1, Whh1, bih1, bhh1, fcW, fcb, out);
}

// Round 3
// 2195.628 us; speedup vs baseline: 1.7266x; 1.7266x over previous
//
#include <hip/hip_runtime.h>

// LSTM: B=2048, T=512, I=1, H=64, L=2, O=1. All fp32.
// Round 3: quarter-row ownership to dodge LLVM's AGPR eviction of large
// per-thread arrays (rounds 1-2 showed ~2.4x VALU inflation from
// v_accvgpr copies whenever a thread holds ~192 weight floats).
//   - 256 blocks x 1024 threads (16 waves/CU, 4/SIMD), BT=8 batch/block.
//   - thread (q = t>>8, r = t&255) owns:
//       L1: 16-float quarter of Whh0 row r      (4 float4)
//       L2: 32-float quarter of [Wih1|Whh1] r   (8 float4)
//     -> 48 persistent floats/thread, ~80 VGPRs total.
//   - partial dots -> LDS p[q][b][r] (lane<->r conflict-free), gate combine
//     in threads 0..511 (thread owns (b,j) c-state), h in LDS broadcast.
//   - 4 barriers/step: L1mv | L1comb | L2mv | L2comb.

#define TT 512
#define HH 64
#define BT 8

__device__ __forceinline__ float sigm(float x) {
    return __builtin_amdgcn_rcpf(1.f + __expf(-x));
}
__device__ __forceinline__ float tanh_f(float x) {
    float xc = fminf(fmaxf(x, -15.f), 15.f);
    float e = __expf(2.f * xc);
    return (e - 1.f) * __builtin_amdgcn_rcpf(e + 1.f);
}
__device__ __forceinline__ float dot4(float4 a, float4 b, float acc) {
    acc = fmaf(a.x, b.x, acc);
    acc = fmaf(a.y, b.y, acc);
    acc = fmaf(a.z, b.z, acc);
    acc = fmaf(a.w, b.w, acc);
    return acc;
}

__global__ __launch_bounds__(1024, 1) void lstm_fused(
    const float* __restrict__ x,
    const float* __restrict__ Wih0, const float* __restrict__ Whh0,
    const float* __restrict__ bih0, const float* __restrict__ bhh0,
    const float* __restrict__ Wih1, const float* __restrict__ Whh1,
    const float* __restrict__ bih1, const float* __restrict__ bhh1,
    const float* __restrict__ fcW, const float* __restrict__ fcb,
    float* __restrict__ out)
{
    __shared__ float xs[BT * TT];        // 16 KB
    __shared__ float hS[BT][128];        // 4 KB: per b, [h1(64)|h2(64)]
    __shared__ float pS[4][BT][256];     // 32 KB: quarter partial sums
    __shared__ float fcw_s[HH];

    const int t  = threadIdx.x;
    const int q  = t >> 8;               // quarter 0..3 (wave-uniform)
    const int r  = t & 255;              // gate-row 0..255
    const int b0 = blockIdx.x * BT;

    // ---- stage x tile: 4096 floats = 1024 float4, one per thread ----
    {
        const float4* xg = (const float4*)(x + (size_t)b0 * TT);
        ((float4*)xs)[t] = xg[t];
    }

    // ---- persistent quarter-row weights: 12 float4 = 48 VGPRs ----
    float4 wq1[4], wq2[8];
    {
        const float4* w1p = (const float4*)(Whh0 + r * HH + q * 16);
        #pragma unroll
        for (int c = 0; c < 4; ++c) wq1[c] = w1p[c];
        const float* b2 = (q < 2) ? (Wih1 + r * HH + q * 32)
                                  : (Whh1 + r * HH + (q - 2) * 32);
        const float4* w2p = (const float4*)b2;
        #pragma unroll
        for (int c = 0; c < 8; ++c) wq2[c] = w2p[c];
    }
    const float wx    = Wih0[r];
    const float bias1 = bih0[r] + bhh0[r];
    const float bias2 = bih1[r] + bhh1[r];
    if (t < HH) fcw_s[t] = fcW[t];

    // ---- zero h state: 8*128 = 1024 floats = 256 float4 ----
    if (t < BT * 32) ((float4*)hS)[t] = make_float4(0.f, 0.f, 0.f, 0.f);

    // combine ownership: thread t<512 owns (cb, cj)
    const int cb = t >> 6;               // wave index; active combine if <8
    const int cj = t & 63;
    float c1 = 0.f, c2 = 0.f;

    __syncthreads();

    for (int step = 0; step < TT; ++step) {
        // ---- phase A: L1 matvec quarter: p[q][b][r] = wq1 . h1[b][16q..] ----
        #pragma unroll
        for (int b = 0; b < BT; ++b) {
            const float4* hq = (const float4*)(&hS[b][q * 16]);
            float a0 = dot4(wq1[0], hq[0], 0.f);
            float a1 = dot4(wq1[1], hq[1], 0.f);
            a0 = dot4(wq1[2], hq[2], a0);
            a1 = dot4(wq1[3], hq[3], a1);
            float acc = a0 + a1;
            if (q == 0) acc += fmaf(wx, xs[b * TT + step], bias1);
            pS[q][b][r] = acc;
        }
        __syncthreads();

        // ---- phase B: L1 gate combine (threads 0..511) ----
        if (cb < BT) {
            float pre0 = ((pS[0][cb][cj]       + pS[1][cb][cj])
                        + (pS[2][cb][cj]       + pS[3][cb][cj]));
            float pre1 = ((pS[0][cb][64 + cj]  + pS[1][cb][64 + cj])
                        + (pS[2][cb][64 + cj]  + pS[3][cb][64 + cj]));
            float pre2 = ((pS[0][cb][128 + cj] + pS[1][cb][128 + cj])
                        + (pS[2][cb][128 + cj] + pS[3][cb][128 + cj]));
            float pre3 = ((pS[0][cb][192 + cj] + pS[1][cb][192 + cj])
                        + (pS[2][cb][192 + cj] + pS[3][cb][192 + cj]));
            float gi = sigm(pre0);
            float gf = sigm(pre1);
            float gg = tanh_f(pre2);
            float go = sigm(pre3);
            c1 = fmaf(gf, c1, gi * gg);
            hS[cb][cj] = go * tanh_f(c1);
        }
        __syncthreads();

        // ---- phase C: L2 matvec quarter over [h1|h2]: k in [32q, 32q+32) ----
        #pragma unroll
        for (int b = 0; b < BT; ++b) {
            const float4* hq = (const float4*)(&hS[b][q * 32]);
            float a0 = dot4(wq2[0], hq[0], 0.f);
            float a1 = dot4(wq2[1], hq[1], 0.f);
            a0 = dot4(wq2[2], hq[2], a0);
            a1 = dot4(wq2[3], hq[3], a1);
            a0 = dot4(wq2[4], hq[4], a0);
            a1 = dot4(wq2[5], hq[5], a1);
            a0 = dot4(wq2[6], hq[6], a0);
            a1 = dot4(wq2[7], hq[7], a1);
            float acc = a0 + a1;
            if (q == 0) acc += bias2;
            pS[q][b][r] = acc;
        }
        __syncthreads();

        // ---- phase D: L2 gate combine ----
        if (cb < BT) {
            float pre0 = ((pS[0][cb][cj]       + pS[1][cb][cj])
                        + (pS[2][cb][cj]       + pS[3][cb][cj]));
            float pre1 = ((pS[0][cb][64 + cj]  + pS[1][cb][64 + cj])
                        + (pS[2][cb][64 + cj]  + pS[3][cb][64 + cj]));
            float pre2 = ((pS[0][cb][128 + cj] + pS[1][cb][128 + cj])
                        + (pS[2][cb][128 + cj] + pS[3][cb][128 + cj]));
            float pre3 = ((pS[0][cb][192 + cj] + pS[1][cb][192 + cj])
                        + (pS[2][cb][192 + cj] + pS[3][cb][192 + cj]));
            float gi = sigm(pre0);
            float gf = sigm(pre1);
            float gg = tanh_f(pre2);
            float go = sigm(pre3);
            c2 = fmaf(gf, c2, gi * gg);
            hS[cb][64 + cj] = go * tanh_f(c2);
        }
        __syncthreads();
    }

    // ---- final FC: out[b] = fcW . h2_final[b] + fcb ----
    if (t < BT) {
        float s = fcb[0];
        #pragma unroll
        for (int j = 0; j < HH; ++j)
            s = fmaf(hS[t][64 + j], fcw_s[j], s);
        out[b0 + t] = s;
    }
}

extern "C" void kernel_launch(void* const* d_in, const int* in_sizes, int n_in,
                              void* d_out, int out_size, void* d_ws, size_t ws_size,
                              hipStream_t stream) {
    const float* x    = (const float*)d_in[0];
    const float* Wih0 = (const float*)d_in[1];
    const float* Whh0 = (const float*)d_in[2];
    const float* bih0 = (const float*)d_in[3];
    const float* bhh0 = (const float*)d_in[4];
    const float* Wih1 = (const float*)d_in[5];
    const float* Whh1 = (const float*)d_in[6];
    const float* bih1 = (const float*)d_in[7];
    const float* bhh1 = (const float*)d_in[8];
    const float* fcW  = (const float*)d_in[9];
    const float* fcb  = (const float*)d_in[10];
    float* out = (float*)d_out;

    lstm_fused<<<dim3(2048 / BT), dim3(1024), 0, stream>>>(
        x, Wih0, Whh0, bih0, bhh0, Wih1, Whh1, bih1, bhh1, fcW, fcb, out);
}

// Round 4
// 788.019 us; speedup vs baseline: 4.8107x; 2.7863x over previous
//
#include <hip/hip_runtime.h>

// LSTM: B=2048, T=512, I=1, H=64, L=2, O=1. fp32 in/out.
// Round 4: MFMA path. Rounds 1-3 proved all scalar-FMA variants are
// LDS-instruction-pipe bound (~1500 broadcast ds_read_b128/CU/step).
// MFMA cuts LDS instrs ~10x: h enters as A-fragments, weights persist as
// B-fragments in registers (AGPR placement is free for MFMA operands).
// fp32 accuracy via bf16 hi+lo 3-product split (residual ~2^-16).
//   - 256 blocks x 512 threads (8 waves, 2/SIMD), BT=8 (M=16 tile, 8 real).
//   - wave w owns gate columns [32w, 32w+32) = 2 N-tiles of 16.
//   - per step: P1 L1-MFMA -> pD | P2 combine -> h1 (A-frags) |
//               P3 L2-MFMA -> pD | P4 combine -> h2 (A-frags).

#define TT 512
#define HH 64
#define BT 8

typedef __attribute__((ext_vector_type(8))) short short8;
typedef __attribute__((ext_vector_type(4))) float f32x4;

__device__ __forceinline__ float sigm(float x) {
    return __builtin_amdgcn_rcpf(1.f + __expf(-x));
}
__device__ __forceinline__ float tanh_f(float x) {
    float xc = fminf(fmaxf(x, -15.f), 15.f);
    float e = __expf(2.f * xc);
    return (e - 1.f) * __builtin_amdgcn_rcpf(e + 1.f);
}
// split fp32 -> bf16 hi + bf16 lo (truncation; residual <= 2^-16 rel)
__device__ __forceinline__ void cvt8(const float* p, short8& hi, short8& lo) {
    #pragma unroll
    for (int i = 0; i < 8; ++i) {
        float v = p[i];
        unsigned short h = (unsigned short)(__float_as_uint(v) >> 16);
        float r = v - __uint_as_float(((unsigned)h) << 16);
        unsigned short l = (unsigned short)(__float_as_uint(r) >> 16);
        hi[i] = (short)h;
        lo[i] = (short)l;
    }
}

__global__ __launch_bounds__(512, 2) void lstm_mfma(
    const float* __restrict__ x,
    const float* __restrict__ Wih0, const float* __restrict__ Whh0,
    const float* __restrict__ bih0, const float* __restrict__ bhh0,
    const float* __restrict__ Wih1, const float* __restrict__ Whh1,
    const float* __restrict__ bih1, const float* __restrict__ bhh1,
    const float* __restrict__ fcW, const float* __restrict__ fcb,
    float* __restrict__ out)
{
    __shared__ float xs[BT][TT + 1];                  // 16.4 KB, row-padded
    __shared__ __align__(16) float pD[256][20];       // 20 KB, [gate][batch+pad]
    __shared__ __align__(16) short aL1[2][2][64][8];  // 4 KB: [kt][hi/lo][lane][elem]
    __shared__ __align__(16) short aL2[4][2][64][8];  // 8 KB
    __shared__ float hF[BT][HH + 1];                  // final h2, fp32
    __shared__ float fcw_s[HH];

    const int t    = threadIdx.x;
    const int lane = t & 63;
    const int w    = t >> 6;        // wave 0..7
    const int nb   = w * 32;        // wave's gate-column base
    const int b0   = blockIdx.x * BT;

    // ---- stage x (coalesced), zero A-frags (h(0)=0 and pad rows 8..15) ----
    for (int i = t; i < BT * TT; i += 512)
        xs[i >> 9][i & (TT - 1)] = x[(size_t)(b0 + (i >> 9)) * TT + (i & (TT - 1))];
    {
        int* z1 = (int*)&aL1[0][0][0][0];
        #pragma unroll
        for (int i = t; i < 1024; i += 512) z1[i] = 0;
        int* z2 = (int*)&aL2[0][0][0][0];
        #pragma unroll
        for (int i = t; i < 2048; i += 512) z2[i] = 0;
    }
    if (t < HH) fcw_s[t] = fcW[t];

    // ---- persistent B fragments (weights, split hi/lo): 96 VGPRs ----
    short8 bh1[2][2], bl1[2][2], bh2[4][2], bl2[4][2];
    {
        const int n_lo = lane & 15;
        const int k8   = (lane >> 4) * 8;
        #pragma unroll
        for (int nt = 0; nt < 2; ++nt) {
            const int n = nb + nt * 16 + n_lo;
            #pragma unroll
            for (int kt = 0; kt < 2; ++kt)
                cvt8(Whh0 + n * HH + kt * 32 + k8, bh1[kt][nt], bl1[kt][nt]);
            #pragma unroll
            for (int kt = 0; kt < 2; ++kt)
                cvt8(Wih1 + n * HH + kt * 32 + k8, bh2[kt][nt], bl2[kt][nt]);
            #pragma unroll
            for (int kt = 0; kt < 2; ++kt)
                cvt8(Whh1 + n * HH + kt * 32 + k8, bh2[2 + kt][nt], bl2[2 + kt][nt]);
        }
    }

    // ---- combine-phase constants: thread t owns (batch cb, hidden cj) ----
    const int cb = t & 7;
    const int cj = t >> 3;
    const float wx0 = Wih0[cj],        wx1 = Wih0[64 + cj],
                wx2 = Wih0[128 + cj],  wx3 = Wih0[192 + cj];
    const float b10 = bih0[cj] + bhh0[cj],       b11 = bih0[64 + cj] + bhh0[64 + cj];
    const float b12 = bih0[128 + cj] + bhh0[128 + cj], b13 = bih0[192 + cj] + bhh0[192 + cj];
    const float b20 = bih1[cj] + bhh1[cj],       b21 = bih1[64 + cj] + bhh1[64 + cj];
    const float b22 = bih1[128 + cj] + bhh1[128 + cj], b23 = bih1[192 + cj] + bhh1[192 + cj];
    // A-frag scatter indices for this thread's h value
    const int skt = cj >> 5;
    const int sla = cb + ((cj >> 3) & 3) * 16;
    const int sel = cj & 7;

    float c1 = 0.f, c2 = 0.f;
    __syncthreads();

    #pragma unroll 1
    for (int step = 0; step < TT; ++step) {
        // ---- P1: L1 MFMA, D[m=batch][n=gate] over K=64 ----
        {
            f32x4 x0 = {0.f, 0.f, 0.f, 0.f}, y0 = x0, x1 = x0, y1 = x0;
            #pragma unroll
            for (int kt = 0; kt < 2; ++kt) {
                short8 ah = *(const short8*)&aL1[kt][0][lane][0];
                short8 al = *(const short8*)&aL1[kt][1][lane][0];
                x0 = __builtin_amdgcn_mfma_f32_16x16x32_bf16(ah, bh1[kt][0], x0, 0, 0, 0);
                y0 = __builtin_amdgcn_mfma_f32_16x16x32_bf16(ah, bl1[kt][0], y0, 0, 0, 0);
                y0 = __builtin_amdgcn_mfma_f32_16x16x32_bf16(al, bh1[kt][0], y0, 0, 0, 0);
                x1 = __builtin_amdgcn_mfma_f32_16x16x32_bf16(ah, bh1[kt][1], x1, 0, 0, 0);
                y1 = __builtin_amdgcn_mfma_f32_16x16x32_bf16(ah, bl1[kt][1], y1, 0, 0, 0);
                y1 = __builtin_amdgcn_mfma_f32_16x16x32_bf16(al, bh1[kt][1], y1, 0, 0, 0);
            }
            f32x4 d0 = x0 + y0, d1 = x1 + y1;
            *(f32x4*)&pD[nb + (lane & 15)][(lane >> 4) * 4] = d0;
            *(f32x4*)&pD[nb + 16 + (lane & 15)][(lane >> 4) * 4] = d1;
        }
        __syncthreads();

        // ---- P2: L1 gate combine -> h1 into aL1 (next step) + aL2 cols 0..63 ----
        {
            float xb = xs[cb][step];
            float pi = pD[cj][cb]        + fmaf(wx0, xb, b10);
            float pf = pD[64 + cj][cb]   + fmaf(wx1, xb, b11);
            float pg = pD[128 + cj][cb]  + fmaf(wx2, xb, b12);
            float po = pD[192 + cj][cb]  + fmaf(wx3, xb, b13);
            float gi = sigm(pi), gf = sigm(pf), gg = tanh_f(pg), go = sigm(po);
            c1 = fmaf(gf, c1, gi * gg);
            float h1 = go * tanh_f(c1);
            unsigned short hh = (unsigned short)(__float_as_uint(h1) >> 16);
            float r = h1 - __uint_as_float(((unsigned)hh) << 16);
            unsigned short hl = (unsigned short)(__float_as_uint(r) >> 16);
            aL1[skt][0][sla][sel] = (short)hh;
            aL1[skt][1][sla][sel] = (short)hl;
            aL2[skt][0][sla][sel] = (short)hh;
            aL2[skt][1][sla][sel] = (short)hl;
        }
        __syncthreads();

        // ---- P3: L2 MFMA over K=128 ([h1 | h2]) ----
        {
            f32x4 x0 = {0.f, 0.f, 0.f, 0.f}, y0 = x0, x1 = x0, y1 = x0;
            #pragma unroll
            for (int kt = 0; kt < 4; ++kt) {
                short8 ah = *(const short8*)&aL2[kt][0][lane][0];
                short8 al = *(const short8*)&aL2[kt][1][lane][0];
                x0 = __builtin_amdgcn_mfma_f32_16x16x32_bf16(ah, bh2[kt][0], x0, 0, 0, 0);
                y0 = __builtin_amdgcn_mfma_f32_16x16x32_bf16(ah, bl2[kt][0], y0, 0, 0, 0);
                y0 = __builtin_amdgcn_mfma_f32_16x16x32_bf16(al, bh2[kt][0], y0, 0, 0, 0);
                x1 = __builtin_amdgcn_mfma_f32_16x16x32_bf16(ah, bh2[kt][1], x1, 0, 0, 0);
                y1 = __builtin_amdgcn_mfma_f32_16x16x32_bf16(ah, bl2[kt][1], y1, 0, 0, 0);
                y1 = __builtin_amdgcn_mfma_f32_16x16x32_bf16(al, bh2[kt][1], y1, 0, 0, 0);
            }
            f32x4 d0 = x0 + y0, d1 = x1 + y1;
            *(f32x4*)&pD[nb + (lane & 15)][(lane >> 4) * 4] = d0;
            *(f32x4*)&pD[nb + 16 + (lane & 15)][(lane >> 4) * 4] = d1;
        }
        __syncthreads();

        // ---- P4: L2 gate combine -> h2 into aL2 cols 64..127 (next step) ----
        {
            float pi = pD[cj][cb]       + b20;
            float pf = pD[64 + cj][cb]  + b21;
            float pg = pD[128 + cj][cb] + b22;
            float po = pD[192 + cj][cb] + b23;
            float gi = sigm(pi), gf = sigm(pf), gg = tanh_f(pg), go = sigm(po);
            c2 = fmaf(gf, c2, gi * gg);
            float h2 = go * tanh_f(c2);
            unsigned short hh = (unsigned short)(__float_as_uint(h2) >> 16);
            float r = h2 - __uint_as_float(((unsigned)hh) << 16);
            unsigned short hl = (unsigned short)(__float_as_uint(r) >> 16);
            aL2[2 + skt][0][sla][sel] = (short)hh;
            aL2[2 + skt][1][sla][sel] = (short)hl;
            hF[cb][cj] = h2;
        }
        __syncthreads();
    }

    // ---- final FC: out[b] = fcW . h2_final[b] + fcb ----
    if (t < BT) {
        float s = fcb[0];
        #pragma unroll 8
        for (int j = 0; j < HH; ++j)
            s = fmaf(hF[t][j], fcw_s[j], s);
        out[b0 + t] = s;
    }
}

extern "C" void kernel_launch(void* const* d_in, const int* in_sizes, int n_in,
                              void* d_out, int out_size, void* d_ws, size_t ws_size,
                              hipStream_t stream) {
    const float* x    = (const float*)d_in[0];
    const float* Wih0 = (const float*)d_in[1];
    const float* Whh0 = (const float*)d_in[2];
    const float* bih0 = (const float*)d_in[3];
    const float* bhh0 = (const float*)d_in[4];
    const float* Wih1 = (const float*)d_in[5];
    const float* Whh1 = (const float*)d_in[6];
    const float* bih1 = (const float*)d_in[7];
    const float* bhh1 = (const float*)d_in[8];
    const float* fcW  = (const float*)d_in[9];
    const float* fcb  = (const float*)d_in[10];
    float* out = (float*)d_out;

    lstm_mfma<<<dim3(2048 / BT), dim3(512), 0, stream>>>(
        x, Wih0, Whh0, bih0, bhh0, Wih1, Whh1, bih1, bhh1, fcW, fcb, out);
}

// Round 5
// 713.632 us; speedup vs baseline: 5.3122x; 1.1042x over previous
//
#include <hip/hip_runtime.h>

// LSTM: B=2048, T=512, I=1, H=64, L=2, O=1. fp32 in/out.
// Round 5: software-pipelined layers. r4 was barrier-bound (4/step, each
// draining LDS latency + transcendental chains). Since h2(t) depends on
// h1(t) and h2(t-1), iteration k computes in ONE MFMA phase:
//     G1 = Whh0*h1(k-1);  G2 = Wih1*h1(k-1) + Whh1*h2(k-2)
// and ONE combine phase: h1(k) from G1, h2(k-1) from G2 (layer-2 skewed).
//   - 2 barriers/step (was 4), A-frags of h1 shared by Whh0+Wih1 (12->8
//     ds_read_b128/wave/step), h1 scattered once, hF only in epilogue.
//   - 256 blocks x 512 threads (8 waves, 2/SIMD), BT=8, wave w owns gate
//     cols [32w,32w+32). fp32 accuracy via bf16 hi+lo 3-product split.

#define TT 512
#define HH 64
#define BT 8

typedef __attribute__((ext_vector_type(8))) short short8;
typedef __attribute__((ext_vector_type(4))) float f32x4;

#define MFMA16 __builtin_amdgcn_mfma_f32_16x16x32_bf16

__device__ __forceinline__ float sigm(float x) {
    return __builtin_amdgcn_rcpf(1.f + __expf(-x));
}
__device__ __forceinline__ float tanh_f(float x) {
    float xc = fminf(fmaxf(x, -15.f), 15.f);
    float e = __expf(2.f * xc);
    return (e - 1.f) * __builtin_amdgcn_rcpf(e + 1.f);
}
// split fp32 -> bf16 hi + bf16 lo (truncation; residual ~2^-16 rel)
__device__ __forceinline__ void cvt8(const float* p, short8& hi, short8& lo) {
    #pragma unroll
    for (int i = 0; i < 8; ++i) {
        float v = p[i];
        unsigned short h = (unsigned short)(__float_as_uint(v) >> 16);
        float r = v - __uint_as_float(((unsigned)h) << 16);
        unsigned short l = (unsigned short)(__float_as_uint(r) >> 16);
        hi[i] = (short)h;
        lo[i] = (short)l;
    }
}
__device__ __forceinline__ void split1(float v, unsigned short& h, unsigned short& l) {
    h = (unsigned short)(__float_as_uint(v) >> 16);
    float r = v - __uint_as_float(((unsigned)h) << 16);
    l = (unsigned short)(__float_as_uint(r) >> 16);
}

__global__ __launch_bounds__(512, 2) void lstm_mfma(
    const float* __restrict__ x,
    const float* __restrict__ Wih0, const float* __restrict__ Whh0,
    const float* __restrict__ bih0, const float* __restrict__ bhh0,
    const float* __restrict__ Wih1, const float* __restrict__ Whh1,
    const float* __restrict__ bih1, const float* __restrict__ bhh1,
    const float* __restrict__ fcW, const float* __restrict__ fcb,
    float* __restrict__ out)
{
    __shared__ float xs[BT][TT + 1];                  // 16.4 KB
    __shared__ __align__(16) float pD[2][256][20];    // 40 KB: [G1/G2][gate][batch+pad]
    __shared__ __align__(16) short aH1[2][2][64][8];  // 4 KB: h1(k-1) A-frags [kt][hi/lo][lane][e]
    __shared__ __align__(16) short aH2[2][2][64][8];  // 4 KB: h2(k-2) A-frags
    __shared__ float hF[BT][HH + 1];
    __shared__ float fcw_s[HH];

    const int t    = threadIdx.x;
    const int lane = t & 63;
    const int w    = t >> 6;        // wave 0..7
    const int nb   = w * 32;        // wave's gate-column base
    const int b0   = blockIdx.x * BT;

    // ---- stage x (coalesced rows), zero A-frags ----
    for (int i = t; i < BT * TT; i += 512)
        xs[i >> 9][i & (TT - 1)] = x[(size_t)(b0 + (i >> 9)) * TT + (i & (TT - 1))];
    {
        int* z1 = (int*)aH1;
        #pragma unroll
        for (int i = t; i < 1024; i += 512) z1[i] = 0;
        int* z2 = (int*)aH2;
        #pragma unroll
        for (int i = t; i < 1024; i += 512) z2[i] = 0;
    }
    if (t < HH) fcw_s[t] = fcW[t];

    // ---- persistent B fragments (hi/lo split): 24 short8 = 96 regs ----
    short8 bh0[2][2], bl0[2][2], bhI[2][2], blI[2][2], bhH[2][2], blH[2][2];
    {
        const int n_lo = lane & 15;
        const int k8   = (lane >> 4) * 8;
        #pragma unroll
        for (int nt = 0; nt < 2; ++nt) {
            const int n = nb + nt * 16 + n_lo;
            #pragma unroll
            for (int kt = 0; kt < 2; ++kt) {
                cvt8(Whh0 + n * HH + kt * 32 + k8, bh0[kt][nt], bl0[kt][nt]);
                cvt8(Wih1 + n * HH + kt * 32 + k8, bhI[kt][nt], blI[kt][nt]);
                cvt8(Whh1 + n * HH + kt * 32 + k8, bhH[kt][nt], blH[kt][nt]);
            }
        }
    }

    // ---- combine constants: thread t owns (batch cb, hidden cj) ----
    const int cb = t & 7;
    const int cj = t >> 3;
    const float wx0 = Wih0[cj],        wx1 = Wih0[64 + cj],
                wx2 = Wih0[128 + cj],  wx3 = Wih0[192 + cj];
    const float b10 = bih0[cj] + bhh0[cj],             b11 = bih0[64 + cj] + bhh0[64 + cj];
    const float b12 = bih0[128 + cj] + bhh0[128 + cj], b13 = bih0[192 + cj] + bhh0[192 + cj];
    const float b20 = bih1[cj] + bhh1[cj],             b21 = bih1[64 + cj] + bhh1[64 + cj];
    const float b22 = bih1[128 + cj] + bhh1[128 + cj], b23 = bih1[192 + cj] + bhh1[192 + cj];
    // A-frag scatter indices for this thread's h value (m=cb, k=cj)
    const int skt = cj >> 5;
    const int sla = cb + ((cj >> 3) & 3) * 16;
    const int sel = cj & 7;

    float c1 = 0.f, c2 = 0.f;
    __syncthreads();

    #pragma unroll 1
    for (int k = 0; k < TT; ++k) {
        // ---- P1: all MFMAs. G1 = Whh0*h1 ; G2 = Wih1*h1 + Whh1*h2 ----
        {
            short8 a1h[2], a1l[2], a2h[2], a2l[2];
            #pragma unroll
            for (int kt = 0; kt < 2; ++kt) {
                a1h[kt] = *(const short8*)&aH1[kt][0][lane][0];
                a1l[kt] = *(const short8*)&aH1[kt][1][lane][0];
                a2h[kt] = *(const short8*)&aH2[kt][0][lane][0];
                a2l[kt] = *(const short8*)&aH2[kt][1][lane][0];
            }
            const f32x4 z = {0.f, 0.f, 0.f, 0.f};
            f32x4 x0 = z, y0 = z, x1 = z, y1 = z;
            #pragma unroll
            for (int kt = 0; kt < 2; ++kt) {
                x0 = MFMA16(a1h[kt], bh0[kt][0], x0, 0, 0, 0);
                y0 = MFMA16(a1h[kt], bl0[kt][0], y0, 0, 0, 0);
                y0 = MFMA16(a1l[kt], bh0[kt][0], y0, 0, 0, 0);
                x1 = MFMA16(a1h[kt], bh0[kt][1], x1, 0, 0, 0);
                y1 = MFMA16(a1h[kt], bl0[kt][1], y1, 0, 0, 0);
                y1 = MFMA16(a1l[kt], bh0[kt][1], y1, 0, 0, 0);
            }
            f32x4 d;
            d = x0 + y0; *(f32x4*)&pD[0][nb +      (lane & 15)][(lane >> 4) * 4] = d;
            d = x1 + y1; *(f32x4*)&pD[0][nb + 16 + (lane & 15)][(lane >> 4) * 4] = d;

            f32x4 u0 = z, v0 = z, u1 = z, v1 = z;
            #pragma unroll
            for (int kt = 0; kt < 2; ++kt) {
                u0 = MFMA16(a1h[kt], bhI[kt][0], u0, 0, 0, 0);
                v0 = MFMA16(a1h[kt], blI[kt][0], v0, 0, 0, 0);
                v0 = MFMA16(a1l[kt], bhI[kt][0], v0, 0, 0, 0);
                u0 = MFMA16(a2h[kt], bhH[kt][0], u0, 0, 0, 0);
                v0 = MFMA16(a2h[kt], blH[kt][0], v0, 0, 0, 0);
                v0 = MFMA16(a2l[kt], bhH[kt][0], v0, 0, 0, 0);
                u1 = MFMA16(a1h[kt], bhI[kt][1], u1, 0, 0, 0);
                v1 = MFMA16(a1h[kt], blI[kt][1], v1, 0, 0, 0);
                v1 = MFMA16(a1l[kt], bhI[kt][1], v1, 0, 0, 0);
                u1 = MFMA16(a2h[kt], bhH[kt][1], u1, 0, 0, 0);
                v1 = MFMA16(a2h[kt], blH[kt][1], v1, 0, 0, 0);
                v1 = MFMA16(a2l[kt], bhH[kt][1], v1, 0, 0, 0);
            }
            d = u0 + v0; *(f32x4*)&pD[1][nb +      (lane & 15)][(lane >> 4) * 4] = d;
            d = u1 + v1; *(f32x4*)&pD[1][nb + 16 + (lane & 15)][(lane >> 4) * 4] = d;
        }
        __syncthreads();

        // ---- P2: combine. h1(k) from G1; h2(k-1) from G2 (skip at k==0) ----
        {
            float xb = xs[cb][k];
            float pi = pD[0][cj][cb]       + fmaf(wx0, xb, b10);
            float pf = pD[0][64 + cj][cb]  + fmaf(wx1, xb, b11);
            float pg = pD[0][128 + cj][cb] + fmaf(wx2, xb, b12);
            float po = pD[0][192 + cj][cb] + fmaf(wx3, xb, b13);
            float gi = sigm(pi), gf = sigm(pf), gg = tanh_f(pg), go = sigm(po);
            c1 = fmaf(gf, c1, gi * gg);
            float h1 = go * tanh_f(c1);
            unsigned short hh, hl;
            split1(h1, hh, hl);
            aH1[skt][0][sla][sel] = (short)hh;
            aH1[skt][1][sla][sel] = (short)hl;
            if (k > 0) {
                float qi = pD[1][cj][cb]       + b20;
                float qf = pD[1][64 + cj][cb]  + b21;
                float qg = pD[1][128 + cj][cb] + b22;
                float qo = pD[1][192 + cj][cb] + b23;
                float hi2 = sigm(qi), hf2 = sigm(qf), hg2 = tanh_f(qg), ho2 = sigm(qo);
                c2 = fmaf(hf2, c2, hi2 * hg2);
                float h2 = ho2 * tanh_f(c2);
                unsigned short h2h, h2l;
                split1(h2, h2h, h2l);
                aH2[skt][0][sla][sel] = (short)h2h;
                aH2[skt][1][sla][sel] = (short)h2l;
            }
        }
        __syncthreads();
    }

    // ---- epilogue: G2 for t=511 -> h2(511) ----
    {
        short8 a1h[2], a1l[2], a2h[2], a2l[2];
        #pragma unroll
        for (int kt = 0; kt < 2; ++kt) {
            a1h[kt] = *(const short8*)&aH1[kt][0][lane][0];
            a1l[kt] = *(const short8*)&aH1[kt][1][lane][0];
            a2h[kt] = *(const short8*)&aH2[kt][0][lane][0];
            a2l[kt] = *(const short8*)&aH2[kt][1][lane][0];
        }
        const f32x4 z = {0.f, 0.f, 0.f, 0.f};
        f32x4 u0 = z, v0 = z, u1 = z, v1 = z;
        #pragma unroll
        for (int kt = 0; kt < 2; ++kt) {
            u0 = MFMA16(a1h[kt], bhI[kt][0], u0, 0, 0, 0);
            v0 = MFMA16(a1h[kt], blI[kt][0], v0, 0, 0, 0);
            v0 = MFMA16(a1l[kt], bhI[kt][0], v0, 0, 0, 0);
            u0 = MFMA16(a2h[kt], bhH[kt][0], u0, 0, 0, 0);
            v0 = MFMA16(a2h[kt], blH[kt][0], v0, 0, 0, 0);
            v0 = MFMA16(a2l[kt], bhH[kt][0], v0, 0, 0, 0);
            u1 = MFMA16(a1h[kt], bhI[kt][1], u1, 0, 0, 0);
            v1 = MFMA16(a1h[kt], blI[kt][1], v1, 0, 0, 0);
            v1 = MFMA16(a1l[kt], bhI[kt][1], v1, 0, 0, 0);
            u1 = MFMA16(a2h[kt], bhH[kt][1], u1, 0, 0, 0);
            v1 = MFMA16(a2h[kt], blH[kt][1], v1, 0, 0, 0);
            v1 = MFMA16(a2l[kt], bhH[kt][1], v1, 0, 0, 0);
        }
        f32x4 d;
        d = u0 + v0; *(f32x4*)&pD[1][nb +      (lane & 15)][(lane >> 4) * 4] = d;
        d = u1 + v1; *(f32x4*)&pD[1][nb + 16 + (lane & 15)][(lane >> 4) * 4] = d;
    }
    __syncthreads();
    {
        float qi = pD[1][cj][cb]       + b20;
        float qf = pD[1][64 + cj][cb]  + b21;
        float qg = pD[1][128 + cj][cb] + b22;
        float qo = pD[1][192 + cj][cb] + b23;
        float hi2 = sigm(qi), hf2 = sigm(qf), hg2 = tanh_f(qg), ho2 = sigm(qo);
        c2 = fmaf(hf2, c2, hi2 * hg2);
        hF[cb][cj] = ho2 * tanh_f(c2);
    }
    __syncthreads();

    // ---- final FC: out[b] = fcW . h2(511)[b] + fcb ----
    if (t < BT) {
        float s = fcb[0];
        #pragma unroll 8
        for (int j = 0; j < HH; ++j)
            s = fmaf(hF[t][j], fcw_s[j], s);
        out[b0 + t] = s;
    }
}

extern "C" void kernel_launch(void* const* d_in, const int* in_sizes, int n_in,
                              void* d_out, int out_size, void* d_ws, size_t ws_size,
                              hipStream_t stream) {
    const float* x    = (const float*)d_in[0];
    const float* Wih0 = (const float*)d_in[1];
    const float* Whh0 = (const float*)d_in[2];
    const float* bih0 = (const float*)d_in[3];
    const float* bhh0 = (const float*)d_in[4];
    const float* Wih1 = (const float*)d_in[5];
    const float* Whh1 = (const float*)d_in[6];
    const float* bih1 = (const float*)d_in[7];
    const float* bhh1 = (const float*)d_in[8];
    const float* fcW  = (const float*)d_in[9];
    const float* fcb  = (const float*)d_in[10];
    float* out = (float*)d_out;

    lstm_mfma<<<dim3(2048 / BT), dim3(512), 0, stream>>>(
        x, Wih0, Whh0, bih0, bhh0, Wih1, Whh1, bih1, bhh1, fcW, fcb, out);
}